// Round 2
// baseline (16.311 us; speedup 1.0000x reference)
//
#include <hip/hip_runtime.h>
#include <math.h>

#define G_EPS 1e-8f

// 256 threads = 4 waves; thread t owns float4 chunk [4t,4t+4) = row b=t>>2,
// quarter q=t&3. Row (16 elems) spans 4 adjacent lanes of ONE wave -> all
// row-level exchange (h for matmul, x for top-k rank) via __shfl_xor, no LDS.
// Single __syncthreads: cross-wave min/max partials + w_p staging.
// Ranking on x = mask + g1 - g2 (sigmoid monotone => same order as soft);
// output is exact {0,1} (ref's stop_gradient expr == hard_bin within 1 ulp).
__global__ __launch_bounds__(256) void GumbelLinear_kernel(
    const float* __restrict__ h_in,
    const float* __restrict__ w_p,
    const float* __restrict__ bias,
    const float* __restrict__ U1,
    const float* __restrict__ U2,
    float* __restrict__ out)
{
    __shared__ float w_s[16][16];   // w_p staged: w_s[k][j]
    __shared__ float pmin[4], pmax[4];

    const int t = threadIdx.x;      // 0..255
    const int q = t & 3;            // quarter within row

    const float4 h4  = reinterpret_cast<const float4*>(h_in)[t];
    const float4 b4  = reinterpret_cast<const float4*>(bias)[t];
    const float4 u14 = reinterpret_cast<const float4*>(U1)[t];
    const float4 u24 = reinterpret_cast<const float4*>(U2)[t];

    if (t < 64) {   // wave 0 stages all of w_p (256 floats)
        reinterpret_cast<float4*>(&w_s[0][0])[t] =
            reinterpret_cast<const float4*>(w_p)[t];
    }

    // ---- global min/max of h: in-reg 4-fold + 64-lane butterfly + 4 partials
    float mn = fminf(fminf(h4.x, h4.y), fminf(h4.z, h4.w));
    float mx = fmaxf(fmaxf(h4.x, h4.y), fmaxf(h4.z, h4.w));
    #pragma unroll
    for (int off = 1; off < 64; off <<= 1) {
        mn = fminf(mn, __shfl_xor(mn, off));
        mx = fmaxf(mx, __shfl_xor(mx, off));
    }
    if ((t & 63) == 0) { pmin[t >> 6] = mn; pmax[t >> 6] = mx; }
    __syncthreads();
    const float gmin = fminf(fminf(pmin[0], pmin[1]), fminf(pmin[2], pmin[3]));
    const float gmax = fmaxf(fmaxf(pmax[0], pmax[1]), fmaxf(pmax[2], pmax[3]));

    // ---- conditional range remap (uniform branch; untaken for N(0,1) data)
    float hx = h4.x, hy = h4.y, hz = h4.z, hw = h4.w;
    if (gmax > 100.0f || gmin < -100.0f) {
        const float r = gmax - gmin;
        hx = fminf(fmaxf((hx - gmin) / r * 0.6f - 0.3f, -0.3f), 0.3f);
        hy = fminf(fmaxf((hy - gmin) / r * 0.6f - 0.3f, -0.3f), 0.3f);
        hz = fminf(fmaxf((hz - gmin) / r * 0.6f - 0.3f, -0.3f), 0.3f);
        hw = fminf(fmaxf((hw - gmin) / r * 0.6f - 0.3f, -0.3f), 0.3f);
    }

    // ---- mask[b][4q..4q+4) = sum_k h[b][k] * w[k][4q..4q+4) + bias
    float4 acc = b4;
    const int jb = q << 2;          // my j base
    #pragma unroll
    for (int m = 0; m < 4; ++m) {
        // h values of quarter (q^m) of my row (m=0: own values, shfl is identity)
        const float v0 = __shfl_xor(hx, m);
        const float v1 = __shfl_xor(hy, m);
        const float v2 = __shfl_xor(hz, m);
        const float v3 = __shfl_xor(hw, m);
        const int kq = (q ^ m) << 2;  // k base of that quarter
        const float4 w0 = *reinterpret_cast<const float4*>(&w_s[kq + 0][jb]);
        const float4 w1 = *reinterpret_cast<const float4*>(&w_s[kq + 1][jb]);
        const float4 w2 = *reinterpret_cast<const float4*>(&w_s[kq + 2][jb]);
        const float4 w3 = *reinterpret_cast<const float4*>(&w_s[kq + 3][jb]);
        acc.x += v0 * w0.x + v1 * w1.x + v2 * w2.x + v3 * w3.x;
        acc.y += v0 * w0.y + v1 * w1.y + v2 * w2.y + v3 * w3.y;
        acc.z += v0 * w0.z + v1 * w1.z + v2 * w2.z + v3 * w3.z;
        acc.w += v0 * w0.w + v1 * w1.w + v2 * w2.w + v3 * w3.w;
    }

    // ---- x = mask + g1 - g2 (sigmoid dropped: monotone, ranking unchanged)
    const float xx = acc.x + logf(-logf(u24.x + G_EPS) + G_EPS) - logf(-logf(u14.x + G_EPS) + G_EPS);
    const float xy = acc.y + logf(-logf(u24.y + G_EPS) + G_EPS) - logf(-logf(u14.y + G_EPS) + G_EPS);
    const float xz = acc.z + logf(-logf(u24.z + G_EPS) + G_EPS) - logf(-logf(u14.z + G_EPS) + G_EPS);
    const float xw = acc.w + logf(-logf(u24.w + G_EPS) + G_EPS) - logf(-logf(u14.w + G_EPS) + G_EPS);

    // ---- top-5 membership: cnt(strictly greater in row) <= 4
    int cx = (xy > xx) + (xz > xx) + (xw > xx);
    int cy = (xx > xy) + (xz > xy) + (xw > xy);
    int cz = (xx > xz) + (xy > xz) + (xw > xz);
    int cw = (xx > xw) + (xy > xw) + (xz > xw);
    #pragma unroll
    for (int m = 1; m < 4; ++m) {
        const float v0 = __shfl_xor(xx, m);
        const float v1 = __shfl_xor(xy, m);
        const float v2 = __shfl_xor(xz, m);
        const float v3 = __shfl_xor(xw, m);
        cx += (v0 > xx) + (v1 > xx) + (v2 > xx) + (v3 > xx);
        cy += (v0 > xy) + (v1 > xy) + (v2 > xy) + (v3 > xy);
        cz += (v0 > xz) + (v1 > xz) + (v2 > xz) + (v3 > xz);
        cw += (v0 > xw) + (v1 > xw) + (v2 > xw) + (v3 > xw);
    }

    float4 o;
    o.x = (cx <= 4) ? 1.0f : 0.0f;
    o.y = (cy <= 4) ? 1.0f : 0.0f;
    o.z = (cz <= 4) ? 1.0f : 0.0f;
    o.w = (cw <= 4) ? 1.0f : 0.0f;
    reinterpret_cast<float4*>(out)[t] = o;
}

extern "C" void kernel_launch(void* const* d_in, const int* in_sizes, int n_in,
                              void* d_out, int out_size, void* d_ws, size_t ws_size,
                              hipStream_t stream) {
    // setup_inputs() order: h, input(unused), w_p, bias, U1, U2 — all float32
    const float* h    = (const float*)d_in[0];
    const float* w_p  = (const float*)d_in[2];
    const float* bias = (const float*)d_in[3];
    const float* U1   = (const float*)d_in[4];
    const float* U2   = (const float*)d_in[5];
    float* out = (float*)d_out;   // 1024 floats

    GumbelLinear_kernel<<<1, 256, 0, stream>>>(h, w_p, bias, U1, U2, out);
}

// Round 3
// 9.601 us; speedup vs baseline: 1.6989x; 1.6989x over previous
//
#include <hip/hip_runtime.h>
#include <math.h>

#define G_EPS 1e-8f

// 1024 threads = 16 waves (4/SIMD on the single CU), one element per thread:
// tid = b*16 + j. A row's 16 elements are 16 ADJACENT LANES of one wave, so
// the matmul h-gather and the top-5 rank count are in-wave __shfl_xor
// (XOR m<16 stays inside the 16-lane group). Single __syncthreads (global
// min/max partials + w_p staging). Rank on x = mask + g1 - g2 (sigmoid is
// monotone); output is exact {0,1} (ref's straight-through expr collapses).
__global__ __launch_bounds__(1024) void GumbelLinear_kernel(
    const float* __restrict__ h_in,
    const float* __restrict__ w_p,
    const float* __restrict__ bias,
    const float* __restrict__ U1,
    const float* __restrict__ U2,
    float* __restrict__ out)
{
    __shared__ float w_s[16][16];     // w_s[k][j]
    __shared__ float pmin[16], pmax[16];

    const int tid = threadIdx.x;      // 0..1023
    const int j   = tid & 15;         // col within row
    const int wid = tid >> 6;         // wave 0..15

    // Issue all global loads up front so latencies overlap.
    const float hv = h_in[tid];
    const float bv = bias[tid];
    const float u1 = U1[tid];
    const float u2 = U2[tid];
    if (tid < 64) {                   // wave 0 stages w_p (256 floats) as float4
        reinterpret_cast<float4*>(&w_s[0][0])[tid] =
            reinterpret_cast<const float4*>(w_p)[tid];
    }

    // ---- global min/max: 64-lane butterfly, 16 wave partials, all-thread fold
    float mn = hv, mx = hv;
    #pragma unroll
    for (int off = 1; off < 64; off <<= 1) {
        mn = fminf(mn, __shfl_xor(mn, off));
        mx = fmaxf(mx, __shfl_xor(mx, off));
    }
    if ((tid & 63) == 0) { pmin[wid] = mn; pmax[wid] = mx; }
    __syncthreads();
    float gmin = pmin[0], gmax = pmax[0];
    #pragma unroll
    for (int i = 1; i < 16; ++i) {    // broadcast LDS reads — conflict-free
        gmin = fminf(gmin, pmin[i]);
        gmax = fmaxf(gmax, pmax[i]);
    }

    // ---- conditional range remap (wave-uniform branch; untaken for N(0,1))
    float hh = hv;
    if (gmax > 100.0f || gmin < -100.0f) {
        hh = fminf(fmaxf((hv - gmin) / (gmax - gmin) * 0.6f - 0.3f, -0.3f), 0.3f);
    }

    // ---- mask[b][j] = sum_k h[b][k] * w[k][j] + bias; k = j^m walks the row
    float acc = bv + hh * w_s[j][j];                 // m = 0 term
    #pragma unroll
    for (int m = 1; m < 16; ++m) {
        const float hk = __shfl_xor(hh, m);          // h[b][j^m]
        acc += hk * w_s[j ^ m][j];                   // distinct banks, 4-lane broadcast
    }

    // ---- x = mask + g1 - g2 = mask + L(u2) - L(u1), L(u)=log(-log(u+eps)+eps)
    const float x = acc + __logf(-__logf(u2 + G_EPS) + G_EPS)
                        - __logf(-__logf(u1 + G_EPS) + G_EPS);

    // ---- top-5 membership: count strictly-greater within the 16-lane row
    int cnt = 0;
    #pragma unroll
    for (int m = 1; m < 16; ++m) {
        cnt += (__shfl_xor(x, m) > x) ? 1 : 0;
    }

    out[tid] = (cnt <= 4) ? 1.0f : 0.0f;
}

extern "C" void kernel_launch(void* const* d_in, const int* in_sizes, int n_in,
                              void* d_out, int out_size, void* d_ws, size_t ws_size,
                              hipStream_t stream) {
    // setup_inputs() order: h, input(unused), w_p, bias, U1, U2 — all float32
    const float* h    = (const float*)d_in[0];
    const float* w_p  = (const float*)d_in[2];
    const float* bias = (const float*)d_in[3];
    const float* U1   = (const float*)d_in[4];
    const float* U2   = (const float*)d_in[5];
    float* out = (float*)d_out;   // 1024 floats

    GumbelLinear_kernel<<<1, 1024, 0, stream>>>(h, w_p, bias, U1, U2, out);
}